// Round 13
// baseline (140.358 us; speedup 1.0000x reference)
//
#include <hip/hip_runtime.h>
#include <math.h>

#define CAP2   511           // max in-edges of target node (expected ~16)
#define CAPS1  512           // max 1-hop node set size
#define CAPN   512           // per-node bucket capacity
#define NBLK1  2048          // scan grid: <=1 edge4 per thread at E=1.6M
#define MBLK   64            // mid grid: cheap barriers (1 arrival/block/line)
#define BMW    4096          // bitmap words (2^17 bits); exact for N < 131072

// R13: decouple grids. k_scan1 = pure 2048-block scan (kernel boundary is a
// free global barrier). k_mid = 64 blocks doing prep+scanC+layers+fin with
// TWO 64-block barriers (one uncontended RMW per block per epoch + 64-lane
// detector) — testing the hypothesis that the invariant ~47us lump in
// R8-R12 was 896-block barrier participation/skew (x3 barriers).
// Cross-barrier data inside k_mid via agent-scope RELAXED (sc1 -> LLC)
// atomics; inter-kernel handoff via plain loads (proven R10). hdr ints:
// [0]=cnt2. ws: hdr(256) | bar(8448) | nodecnt(2048) | partials | L2_src |
// L2_ea | buck(2MB) | xl2. First 10752 B zeroed by hipMemsetAsync each call.

__device__ __forceinline__ int aload_i(const int* p) {
    return __hip_atomic_load((int*)p, __ATOMIC_RELAXED, __HIP_MEMORY_SCOPE_AGENT);
}
__device__ __forceinline__ float aload_f(const float* p) {
    return __hip_atomic_load((float*)p, __ATOMIC_RELAXED, __HIP_MEMORY_SCOPE_AGENT);
}
__device__ __forceinline__ void astore_f(float* p, float v) {
    __hip_atomic_store(p, v, __ATOMIC_RELAXED, __HIP_MEMORY_SCOPE_AGENT);
}
__device__ __forceinline__ unsigned long long aload_u64(const unsigned long long* p) {
    return __hip_atomic_load((unsigned long long*)p, __ATOMIC_RELAXED, __HIP_MEMORY_SCOPE_AGENT);
}
__device__ __forceinline__ void astore_u64(unsigned long long* p, unsigned long long v) {
    __hip_atomic_store(p, v, __ATOMIC_RELAXED, __HIP_MEMORY_SCOPE_AGENT);
}

// 64-block barrier: each block bumps its OWN line (zero RMW serialization);
// block 0's wave 0 sums the 64 lines in one parallel load + butterfly, then
// publishes the generation. All RELAXED (no cache-maintenance ops).
__device__ __forceinline__ void grid_sync64(int* bar, int epoch) {
    __syncthreads();   // drains vmcnt: this block's sc1 stores are at LLC
    if (threadIdx.x == 0)
        __hip_atomic_fetch_add(&bar[32 * blockIdx.x], 1,
                               __ATOMIC_RELAXED, __HIP_MEMORY_SCOPE_AGENT);
    if (blockIdx.x == 0 && threadIdx.x < 64) {
        int lane = threadIdx.x;
        int target = (epoch + 1) * MBLK;
        for (;;) {
            int v = __hip_atomic_load(&bar[32 * lane], __ATOMIC_RELAXED,
                                      __HIP_MEMORY_SCOPE_AGENT);
            for (int o = 32; o >= 1; o >>= 1) v += __shfl_xor(v, o, 64);
            if (v >= target) break;
            __builtin_amdgcn_s_sleep(1);
        }
        if (lane == 0)
            __hip_atomic_store(&bar[32 * MBLK], epoch + 1,
                               __ATOMIC_RELAXED, __HIP_MEMORY_SCOPE_AGENT);
    } else if (threadIdx.x == 0) {
        while (__hip_atomic_load(&bar[32 * MBLK], __ATOMIC_RELAXED,
                                 __HIP_MEMORY_SCOPE_AGENT) < epoch + 1)
            __builtin_amdgcn_s_sleep(2);
    }
    __syncthreads();
}

// ---- scan 1: pure (no election): target in-edges + per-block ea sums -------
__global__ __launch_bounds__(256)
void k_scan1(const int* __restrict__ ei, const float* __restrict__ ea,
             const int* __restrict__ tptr, int E,
             int* hdr, int* L2_src, float* L2_ea, float* partials) {
    int tid = threadIdx.x, lane = tid & 63, wq = tid >> 6;
    int gid = blockIdx.x * 256 + tid;
    int t = tptr[0];
    int E4 = E >> 2;
    float local = 0.f;
    __shared__ float wsum[4];

    for (int e4 = gid; e4 < E4; e4 += NBLK1 * 256) {   // <=1 iter at E=1.6M
        int4   d = ((const int4*)(ei + E))[e4];
        float4 a = ((const float4*)ea)[e4];
        local += a.x + a.y + a.z + a.w;
        int eb = e4 * 4;
        if (d.x == t) { int p = atomicAdd(&hdr[0], 1); if (p < CAP2) { L2_src[p] = ei[eb];     L2_ea[p] = a.x; } }
        if (d.y == t) { int p = atomicAdd(&hdr[0], 1); if (p < CAP2) { L2_src[p] = ei[eb + 1]; L2_ea[p] = a.y; } }
        if (d.z == t) { int p = atomicAdd(&hdr[0], 1); if (p < CAP2) { L2_src[p] = ei[eb + 2]; L2_ea[p] = a.z; } }
        if (d.w == t) { int p = atomicAdd(&hdr[0], 1); if (p < CAP2) { L2_src[p] = ei[eb + 3]; L2_ea[p] = a.w; } }
    }
    if (gid == 0) {                                    // tail (E % 4)
        for (int e = E4 * 4; e < E; e++) {
            float a = ea[e];
            local += a;
            if (ei[E + e] == t) { int p = atomicAdd(&hdr[0], 1); if (p < CAP2) { L2_src[p] = ei[e]; L2_ea[p] = a; } }
        }
    }
    for (int o = 32; o >= 1; o >>= 1) local += __shfl_xor(local, o, 64);
    if (lane == 0) wsum[wq] = local;
    __syncthreads();
    if (tid == 0) partials[blockIdx.x] = wsum[0] + wsum[1] + wsum[2] + wsum[3];
}

// ---- mid: prep + scanC + layers + fin, 64 blocks, 2 cheap barriers ---------
__global__ __launch_bounds__(256)
void k_mid(const float* __restrict__ x, const int* __restrict__ ei,
           const float* __restrict__ ea, const int* __restrict__ tptr,
           const float* __restrict__ Wl1, const float* __restrict__ bl1,
           const float* __restrict__ Wr1, const float* __restrict__ br1,
           const float* __restrict__ We1, const float* __restrict__ att1,
           const float* __restrict__ b1,
           const float* __restrict__ Wl2, const float* __restrict__ bl2,
           const float* __restrict__ Wr2, const float* __restrict__ br2,
           const float* __restrict__ We2, const float* __restrict__ att2,
           const float* __restrict__ b2,
           const float* __restrict__ Wf, const float* __restrict__ bf,
           int E,
           const int* __restrict__ hdr, int* bar, int* nodecnt,
           const float* __restrict__ partials,
           const int* __restrict__ L2_src, const float* __restrict__ L2_ea,
           unsigned long long* buck, float* xl2, float* out) {
    int tid = threadIdx.x, lane = tid & 63, wq = tid >> 6;
    int bid = blockIdx.x;
    int gid = bid * 256 + tid;
    int t = tptr[0];
    int E4 = E >> 2;

    __shared__ float wsum[4];
    __shared__ int   s1[CAPS1];
    __shared__ int   l2idx[CAP2];
    __shared__ int   esrc[CAPN + 1];
    __shared__ float eea[CAPN + 1];
    __shared__ float xsA[CAPN + 1], xsB[CAPN + 1];
    __shared__ float scores[CAPN + 1];
    __shared__ float part[4][64];
    __shared__ float hrow[64];
    __shared__ float xr2s[64];
    __shared__ int   bitmap[BMW];      // scanC; reused as xl2sh in fin
    __shared__ float m_sh, d_sh, eam_sh;
    __shared__ int   n_sh;

    // ---- prep (all 64 blocks, redundantly; plain loads, kernel boundary) ---
    int c2 = hdr[0]; if (c2 > CAP2) c2 = CAP2;
    {
        float local = 0.f;
        for (int k = tid; k < NBLK1; k += 256) local += partials[k];
        for (int o = 32; o >= 1; o >>= 1) local += __shfl_xor(local, o, 64);
        if (lane == 0) wsum[wq] = local;
        __syncthreads();
        if (tid == 0) eam_sh = (wsum[0] + wsum[1] + wsum[2] + wsum[3]) / (float)E;

        if (wq == 0) {
            if (c2 <= 64) {                 // ballot fast path
                int v = (lane < c2) ? L2_src[lane] : -1;
                int first = lane;
                #pragma unroll
                for (int j = 0; j < 64; j++) {
                    int vj = __shfl(v, j);
                    if (j < first && vj == v) first = j;
                }
                bool isfirst = (lane < c2) && (first == lane) && (v != t);
                unsigned long long bfm = __ballot(isfirst);
                int myidx = (v == t) ? 0
                            : (1 + (int)__popcll(bfm & ((1ull << lane) - 1)));
                int idx = __shfl(myidx, first);
                if (lane < c2) l2idx[lane] = idx;
                if (isfirst) s1[myidx] = v;
                if (lane == 0) { s1[0] = t; n_sh = 1 + (int)__popcll(bfm); }
            } else if (lane == 0) {         // serial fallback
                s1[0] = t;
                int n = 1;
                for (int k = 0; k < c2; k++) {
                    int v = L2_src[k];
                    int idx = -1;
                    for (int j = 0; j < n; j++) if (s1[j] == v) { idx = j; break; }
                    if (idx < 0) { idx = n; s1[n] = v; n++; }
                    l2idx[k] = idx;
                }
                n_sh = n;
            }
        }
        for (int w = tid; w < BMW; w += 256) bitmap[w] = 0;
        __syncthreads();
        int n_s1 = n_sh;
        for (int j = tid; j < n_s1; j += 256) {
            int u = s1[j];
            atomicOr(&bitmap[(u >> 5) & (BMW - 1)], 1 << (u & 31));
        }
        __syncthreads();

        // ---- scanC: bitmap test, verify on hit, push to per-node bucket ----
        for (int e4 = gid; e4 < E4; e4 += MBLK * 256) {
            int4 d = ((const int4*)(ei + E))[e4];
            int eb = e4 * 4;
            int dd[4] = {d.x, d.y, d.z, d.w};
            #pragma unroll
            for (int q = 0; q < 4; q++) {
                int dv = dd[q];
                if (bitmap[(dv >> 5) & (BMW - 1)] & (1 << (dv & 31))) {
                    int idx = -1;
                    for (int j = 0; j < n_s1; j++) if (s1[j] == dv) { idx = j; break; }
                    if (idx >= 0) {
                        int slot = __hip_atomic_fetch_add(&nodecnt[idx], 1,
                                     __ATOMIC_RELAXED, __HIP_MEMORY_SCOPE_AGENT);
                        if (slot < CAPN) {
                            unsigned long long pk =
                                ((unsigned long long)__float_as_uint(ea[eb + q]) << 32) |
                                (unsigned)ei[eb + q];
                            astore_u64(&buck[(size_t)idx * CAPN + slot], pk);
                        }
                    }
                }
            }
        }
        if (gid == 0) {
            for (int e = E4 * 4; e < E; e++) {
                int dv = ei[E + e];
                int idx = -1;
                for (int j = 0; j < n_s1; j++) if (s1[j] == dv) { idx = j; break; }
                if (idx >= 0) {
                    int slot = __hip_atomic_fetch_add(&nodecnt[idx], 1,
                                 __ATOMIC_RELAXED, __HIP_MEMORY_SCOPE_AGENT);
                    if (slot < CAPN) {
                        unsigned long long pk =
                            ((unsigned long long)__float_as_uint(ea[e]) << 32) |
                            (unsigned)ei[e];
                        astore_u64(&buck[(size_t)idx * CAPN + slot], pk);
                    }
                }
            }
        }
    }
    grid_sync64(bar, 0);

    int n_s1 = n_sh;
    float eam = eam_sh;

    // ---- layers: layer 1 per node + fused layer-2 transforms ---------------
    for (int node = bid; node < n_s1; node += MBLK) {
        int v = s1[node];
        int cnt = aload_i(&nodecnt[node]); if (cnt > CAPN) cnt = CAPN;
        for (int k = tid; k < cnt; k += 256) {
            unsigned long long pk = aload_u64(&buck[(size_t)node * CAPN + k]);
            esrc[k] = (int)(unsigned)(pk & 0xffffffffull);
            eea[k]  = __uint_as_float((unsigned)(pk >> 32));
        }
        __syncthreads();
        int nE = cnt;
        if (tid == 0) { esrc[nE] = v; eea[nE] = eam; }   // self-loop
        __syncthreads();
        nE += 1;

        const float2* x2 = (const float2*)x;
        for (int j = tid; j < nE; j += 256) {            // parallel x gather
            float2 xv = x2[esrc[j]];
            xsA[j] = xv.x; xsB[j] = xv.y;
        }
        __syncthreads();

        float wl0 = Wl1[lane], wl1w = Wl1[64 + lane], bl = bl1[lane];
        float we = We1[lane], at = att1[lane];
        float2 xv = x2[v];
        float xr = xv.x * Wr1[lane] + xv.y * Wr1[64 + lane] + br1[lane];

        for (int k = wq; k < nE; k += 4) {               // scores
            float xl = xsA[k] * wl0 + xsB[k] * wl1w + bl;
            float ev = xl + xr + eea[k] * we;
            ev = ev > 0.f ? ev : 0.2f * ev;
            float p = ev * at;
            for (int o = 32; o >= 1; o >>= 1) p += __shfl_xor(p, o, 64);
            if (lane == 0) scores[k] = p;
        }
        __syncthreads();

        if (wq == 0) {                                   // softmax stats
            float m = -3.4e38f;
            for (int k = lane; k < nE; k += 64) m = fmaxf(m, scores[k]);
            for (int o = 32; o >= 1; o >>= 1) m = fmaxf(m, __shfl_xor(m, o, 64));
            float d = 0.f;
            for (int k = lane; k < nE; k += 64) d += expf(scores[k] - m);
            for (int o = 32; o >= 1; o >>= 1) d += __shfl_xor(d, o, 64);
            if (lane == 0) { m_sh = m; d_sh = d; }
        }
        __syncthreads();
        float m = m_sh, dinv = 1.f / d_sh;

        float acc = 0.f;                                 // weighted sum
        for (int k = wq; k < nE; k += 4) {
            float xl = xsA[k] * wl0 + xsB[k] * wl1w + bl;
            acc += expf(scores[k] - m) * dinv * xl;
        }
        part[wq][lane] = acc;
        __syncthreads();
        if (tid < 64) {
            float h = part[0][lane] + part[1][lane] + part[2][lane] + part[3][lane] + b1[lane];
            hrow[lane] = h > 0.f ? h : 0.f;
        }
        __syncthreads();

        // fused: xl2[node] = Wl2^T hrow + bl2 (k-split across waves), sc1 out
        float p = 0.f;
        int k0 = 16 * wq;
        for (int k = k0; k < k0 + 16; k++) p += hrow[k] * Wl2[k * 64 + lane];
        part[wq][lane] = p;
        __syncthreads();
        if (tid < 64)
            astore_f(&xl2[node * 64 + lane],
                     part[0][lane] + part[1][lane] + part[2][lane] + part[3][lane] + bl2[lane]);

        if (node == 0) {                                 // target transform -> LDS
            __syncthreads();
            float p2 = 0.f;
            for (int k = k0; k < k0 + 16; k++) p2 += hrow[k] * Wr2[k * 64 + lane];
            part[wq][lane] = p2;
            __syncthreads();
            if (tid < 64)
                xr2s[lane] = part[0][lane] + part[1][lane] + part[2][lane] + part[3][lane] + br2[lane];
        }
        __syncthreads();
    }
    grid_sync64(bar, 1);

    // ---- fin (block 0, all 4 waves): layer-2 softmax + relu + head ---------
    if (bid == 0) {
        int nE2 = c2;
        float* xl2sh = (float*)bitmap;                   // reuse 16 KB
        int rows = n_s1 < 64 ? n_s1 : 64;
        for (int i = tid; i < rows * 64; i += 256) xl2sh[i] = aload_f(&xl2[i]);
        for (int j = tid; j < nE2; j += 256) eea[j] = L2_ea[j];
        __syncthreads();

        float we = We2[lane], at = att2[lane], xr = xr2s[lane];
        for (int j = wq; j <= nE2; j += 4) {             // scores over waves
            int   idx = (j < nE2) ? l2idx[j] : 0;
            float eav = (j < nE2) ? eea[j]   : eam;
            float xlv = (idx < 64) ? xl2sh[idx * 64 + lane]
                                   : aload_f(&xl2[idx * 64 + lane]);
            float ev = xlv + xr + eav * we;
            ev = ev > 0.f ? ev : 0.2f * ev;
            float p = ev * at;
            for (int o = 32; o >= 1; o >>= 1) p += __shfl_xor(p, o, 64);
            if (lane == 0) scores[j] = p;
        }
        __syncthreads();

        if (wq == 0) {                                   // softmax stats
            int tot = nE2 + 1;
            float m = -3.4e38f;
            for (int j = lane; j < tot; j += 64) m = fmaxf(m, scores[j]);
            for (int o = 32; o >= 1; o >>= 1) m = fmaxf(m, __shfl_xor(m, o, 64));
            float d = 0.f;
            for (int j = lane; j < tot; j += 64) d += expf(scores[j] - m);
            for (int o = 32; o >= 1; o >>= 1) d += __shfl_xor(d, o, 64);
            if (lane == 0) { m_sh = m; d_sh = d; }
        }
        __syncthreads();
        float m = m_sh, dinv = 1.f / d_sh;

        float acc = 0.f;                                 // weighted sum over waves
        for (int j = wq; j <= nE2; j += 4) {
            int idx = (j < nE2) ? l2idx[j] : 0;
            float xlv = (idx < 64) ? xl2sh[idx * 64 + lane]
                                   : aload_f(&xl2[idx * 64 + lane]);
            acc += expf(scores[j] - m) * dinv * xlv;
        }
        part[wq][lane] = acc;
        __syncthreads();
        if (tid < 64) {
            float h = part[0][lane] + part[1][lane] + part[2][lane] + part[3][lane] + b2[lane];
            hrow[lane] = h > 0.f ? h : 0.f;
        }
        __syncthreads();
        if (tid < 128) {                                 // head: [64]@[64,128]+bf
            float r = bf[tid];
            for (int c = 0; c < 64; c++) r += hrow[c] * Wf[c * 128 + tid];
            out[tid] = r;
        }
    }
}

extern "C" void kernel_launch(void* const* d_in, const int* in_sizes, int n_in,
                              void* d_out, int out_size, void* d_ws, size_t ws_size,
                              hipStream_t stream) {
    const float* x    = (const float*)d_in[0];
    const int*   ei   = (const int*)  d_in[1];
    const float* ea   = (const float*)d_in[2];
    const int*   tptr = (const int*)  d_in[3];
    const float* Wl1  = (const float*)d_in[4];
    const float* bl1  = (const float*)d_in[5];
    const float* Wr1  = (const float*)d_in[6];
    const float* br1  = (const float*)d_in[7];
    const float* We1  = (const float*)d_in[8];
    const float* att1 = (const float*)d_in[9];
    const float* b1   = (const float*)d_in[10];
    const float* Wl2  = (const float*)d_in[11];
    const float* bl2  = (const float*)d_in[12];
    const float* Wr2  = (const float*)d_in[13];
    const float* br2  = (const float*)d_in[14];
    const float* We2  = (const float*)d_in[15];
    const float* att2 = (const float*)d_in[16];
    const float* b2   = (const float*)d_in[17];
    const float* Wf   = (const float*)d_in[18];
    const float* bf   = (const float*)d_in[19];

    int E = in_sizes[2];

    char* base = (char*)d_ws;
    int*   hdr      = (int*)base;   base += 256;
    int*   bar      = (int*)base;   base += 8448;   // 64 leaf lines + gen line
    int*   nodecnt  = (int*)base;   base += 2048;   // per-node bucket counters
    float* partials = (float*)base; base += NBLK1 * sizeof(float);
    int*   L2_src   = (int*)base;   base += 512 * sizeof(int);
    float* L2_ea    = (float*)base; base += 512 * sizeof(float);
    unsigned long long* buck = (unsigned long long*)base;
    base += (size_t)CAPS1 * CAPN * sizeof(unsigned long long);   // 2 MB
    float* xl2      = (float*)base; base += (size_t)CAPS1 * 64 * sizeof(float);

    // Load-bearing: ws re-poisoned to 0xAA before every timed launch;
    // hdr + barrier epochs + bucket counters must start at 0.
    hipMemsetAsync(hdr, 0, 256 + 8448 + 2048, stream);

    hipLaunchKernelGGL(k_scan1, dim3(NBLK1), dim3(256), 0, stream,
                       ei, ea, tptr, E, hdr, L2_src, L2_ea, partials);
    hipLaunchKernelGGL(k_mid, dim3(MBLK), dim3(256), 0, stream,
                       x, ei, ea, tptr,
                       Wl1, bl1, Wr1, br1, We1, att1, b1,
                       Wl2, bl2, Wr2, br2, We2, att2, b2,
                       Wf, bf, E,
                       hdr, bar, nodecnt, partials,
                       L2_src, L2_ea, buck, xl2, (float*)d_out);
}

// Round 14
// 129.977 us; speedup vs baseline: 1.0799x; 1.0799x over previous
//
#include <hip/hip_runtime.h>
#include <math.h>

#define CAP2   511           // max in-edges of target node (expected ~16)
#define CAPS1  512           // max 1-hop node set size
#define CAPN   512           // per-node bucket capacity
#define NBLK   1024          // persistent grid: exactly 4 blocks/CU (capacity proven R12)
#define NLEAF  64            // barrier leaf lines (16 arrivals each at NBLK=1024)
#define BMW    4096          // bitmap words (2^17 bits); exact for N < 131072
#define DCI    2             // LDS dst-cache depth (covers E <= 2.09M)

// R14: kill the LAST redundant global stream — scanC's re-read of dst.
// Phase 1 caches each thread's <=DCI dst4 values in LDS (8 KB, unioned with
// the phase-4 edge arrays); phase 3 reads dst from LDS + bitmap, touching
// global only on true hits (~300 grid-wide). Everything else = R12.
// ws: hdr(256) | bar(8448) | nodecnt(2048) | partials | L2_src | L2_ea |
// buck(2MB) | xl2. First 10752+ B zeroed by hipMemsetAsync each call.
// Cross-phase data via agent-scope RELAXED (sc1 -> LLC) atomics; barrier is
// fence-free (syncthreads drains vmcnt before arrival RMW). (R7-R13, absmax 0)

__device__ __forceinline__ int aload_i(const int* p) {
    return __hip_atomic_load((int*)p, __ATOMIC_RELAXED, __HIP_MEMORY_SCOPE_AGENT);
}
__device__ __forceinline__ void astore_i(int* p, int v) {
    __hip_atomic_store(p, v, __ATOMIC_RELAXED, __HIP_MEMORY_SCOPE_AGENT);
}
__device__ __forceinline__ float aload_f(const float* p) {
    return __hip_atomic_load((float*)p, __ATOMIC_RELAXED, __HIP_MEMORY_SCOPE_AGENT);
}
__device__ __forceinline__ void astore_f(float* p, float v) {
    __hip_atomic_store(p, v, __ATOMIC_RELAXED, __HIP_MEMORY_SCOPE_AGENT);
}
__device__ __forceinline__ unsigned long long aload_u64(const unsigned long long* p) {
    return __hip_atomic_load((unsigned long long*)p, __ATOMIC_RELAXED, __HIP_MEMORY_SCOPE_AGENT);
}
__device__ __forceinline__ void astore_u64(unsigned long long* p, unsigned long long v) {
    __hip_atomic_store(p, v, __ATOMIC_RELAXED, __HIP_MEMORY_SCOPE_AGENT);
}

// Flat-fanout monotonic barrier: 64 leaf lines (16 serialized RMWs each at
// NBLK=1024); block 0's wave 0 detects via one 64-lane load + butterfly.
__device__ __forceinline__ void grid_sync(int* bar, int epoch) {
    __syncthreads();
    if (threadIdx.x < 64) {
        int lane = threadIdx.x;
        if (lane == 0)
            __hip_atomic_fetch_add(&bar[32 * (blockIdx.x & (NLEAF - 1))], 1,
                                   __ATOMIC_RELAXED, __HIP_MEMORY_SCOPE_AGENT);
        if (blockIdx.x == 0) {
            int target = (epoch + 1) * NBLK;
            for (;;) {
                int v = __hip_atomic_load(&bar[32 * lane], __ATOMIC_RELAXED,
                                          __HIP_MEMORY_SCOPE_AGENT);
                for (int o = 32; o >= 1; o >>= 1) v += __shfl_xor(v, o, 64);
                if (v >= target) break;
                __builtin_amdgcn_s_sleep(1);
            }
            if (lane == 0)
                __hip_atomic_store(&bar[32 * NLEAF], epoch + 1,
                                   __ATOMIC_RELAXED, __HIP_MEMORY_SCOPE_AGENT);
        } else if (lane == 0) {
            while (__hip_atomic_load(&bar[32 * NLEAF], __ATOMIC_RELAXED,
                                     __HIP_MEMORY_SCOPE_AGENT) < epoch + 1)
                __builtin_amdgcn_s_sleep(2);
        }
    }
    __syncthreads();
}

__global__ __launch_bounds__(256, 4)
void k_mega(const float* __restrict__ x, const int* __restrict__ ei,
            const float* __restrict__ ea, const int* __restrict__ tptr,
            const float* __restrict__ Wl1, const float* __restrict__ bl1,
            const float* __restrict__ Wr1, const float* __restrict__ br1,
            const float* __restrict__ We1, const float* __restrict__ att1,
            const float* __restrict__ b1,
            const float* __restrict__ Wl2, const float* __restrict__ bl2,
            const float* __restrict__ Wr2, const float* __restrict__ br2,
            const float* __restrict__ We2, const float* __restrict__ att2,
            const float* __restrict__ b2,
            const float* __restrict__ Wf, const float* __restrict__ bf,
            int E,
            int* hdr, int* bar, int* nodecnt, float* partials,
            int* L2_src, float* L2_ea,
            unsigned long long* buck,
            float* xl2, float* out) {
    int tid = threadIdx.x, lane = tid & 63, wq = tid >> 6;
    int bid = blockIdx.x;
    int gid = bid * 256 + tid;
    const int gstride = NBLK * 256;

    __shared__ float wsum[4];
    __shared__ int   s1[CAPS1];
    __shared__ int   l2idx[CAP2];
    // union: phases 1-3 use dstc4 (LDS dst cache); phases 4-5 use edge arrays
    __shared__ int4  ubuf[514];                       // 8224 B
    int4*  dstc4 = ubuf;                              // [DCI*256] int4
    int*   esrc  = (int*)ubuf;                        // [513]
    float* eea   = (float*)ubuf + 513;                // [513]
    float* xsA   = (float*)ubuf + 1026;               // [513]
    float* xsB   = (float*)ubuf + 1539;               // [513]
    __shared__ float scores[CAPN + 1];
    __shared__ float part[4][64];
    __shared__ float hrow[64];
    __shared__ float xr2s[64];
    __shared__ int   bitmap[BMW];      // phase 3; reused as xl2sh in phase 5
    __shared__ float m_sh, d_sh, eam_sh;
    __shared__ int   n_sh;

    const int4*   dst4 = (const int4*)(ei + E);
    const float4* ea4  = (const float4*)ea;
    int E4 = E >> 2;
    int t = tptr[0];

    // ------- phase 1: scanA (target in-edges + ea sums) + LDS dst cache -----
    {
        float local = 0.f;
        int it = 0;
        for (int e4 = gid; e4 < E4; e4 += gstride, it++) {
            int4 d = dst4[e4];
            float4 a = ea4[e4];
            if (it < DCI) dstc4[it * 256 + tid] = d;   // cache for phase 3
            local += a.x + a.y + a.z + a.w;
            int eb = e4 * 4;
            if (d.x == t) { int p = atomicAdd(&hdr[0], 1); if (p < CAP2) { astore_i(&L2_src[p], ei[eb]);     astore_f(&L2_ea[p], a.x); } }
            if (d.y == t) { int p = atomicAdd(&hdr[0], 1); if (p < CAP2) { astore_i(&L2_src[p], ei[eb + 1]); astore_f(&L2_ea[p], a.y); } }
            if (d.z == t) { int p = atomicAdd(&hdr[0], 1); if (p < CAP2) { astore_i(&L2_src[p], ei[eb + 2]); astore_f(&L2_ea[p], a.z); } }
            if (d.w == t) { int p = atomicAdd(&hdr[0], 1); if (p < CAP2) { astore_i(&L2_src[p], ei[eb + 3]); astore_f(&L2_ea[p], a.w); } }
        }
        if (gid == 0) {                  // tail (E % 4)
            for (int e = E4 * 4; e < E; e++) {
                float a = ea[e];
                local += a;
                if (ei[E + e] == t) { int p = atomicAdd(&hdr[0], 1); if (p < CAP2) { astore_i(&L2_src[p], ei[e]); astore_f(&L2_ea[p], a); } }
            }
        }
        for (int o = 32; o >= 1; o >>= 1) local += __shfl_xor(local, o, 64);
        if (lane == 0) wsum[wq] = local;
        __syncthreads();
        if (tid == 0) astore_f(&partials[bid], wsum[0] + wsum[1] + wsum[2] + wsum[3]);
    }
    grid_sync(bar, 0);

    // ------- phase 2+3: ea_sum reduce, ballot dedupe, bitmap, scanC(LDS) ----
    int c2 = aload_i(&hdr[0]); if (c2 > CAP2) c2 = CAP2;
    {
        float local = 0.f;
        for (int k = tid; k < NBLK; k += 256) local += aload_f(&partials[k]);
        for (int o = 32; o >= 1; o >>= 1) local += __shfl_xor(local, o, 64);
        if (lane == 0) wsum[wq] = local;
        __syncthreads();
        if (tid == 0) eam_sh = (wsum[0] + wsum[1] + wsum[2] + wsum[3]) / (float)E;

        if (wq == 0) {                    // dedupe (every block, redundantly)
            if (c2 <= 64) {
                int v = (lane < c2) ? aload_i(&L2_src[lane]) : -1;
                int first = lane;
                #pragma unroll
                for (int j = 0; j < 64; j++) {
                    int vj = __shfl(v, j);
                    if (j < first && vj == v) first = j;
                }
                bool isfirst = (lane < c2) && (first == lane) && (v != t);
                unsigned long long bfm = __ballot(isfirst);
                int myidx = (v == t) ? 0
                            : (1 + (int)__popcll(bfm & ((1ull << lane) - 1)));
                int idx = __shfl(myidx, first);
                if (lane < c2) l2idx[lane] = idx;
                if (isfirst) s1[myidx] = v;
                if (lane == 0) { s1[0] = t; n_sh = 1 + (int)__popcll(bfm); }
            } else if (lane == 0) {        // serial fallback
                s1[0] = t;
                int n = 1;
                for (int k = 0; k < c2; k++) {
                    int v = aload_i(&L2_src[k]);
                    int idx = -1;
                    for (int j = 0; j < n; j++) if (s1[j] == v) { idx = j; break; }
                    if (idx < 0) { idx = n; s1[n] = v; n++; }
                    l2idx[k] = idx;
                }
                n_sh = n;
            }
        }
        for (int w = tid; w < BMW; w += 256) bitmap[w] = 0;
        __syncthreads();
        int n_s1 = n_sh;
        for (int j = tid; j < n_s1; j += 256) {
            int u = s1[j];
            atomicOr(&bitmap[(u >> 5) & (BMW - 1)], 1 << (u & 31));
        }
        __syncthreads();

        // scanC: dst from LDS cache (zero global dst loads for it<DCI);
        // global touched only on true hits (~300 grid-wide).
        int it = 0;
        for (int e4 = gid; e4 < E4; e4 += gstride, it++) {
            int4 d = (it < DCI) ? dstc4[it * 256 + tid] : dst4[e4];
            int eb = e4 * 4;
            int dd[4] = {d.x, d.y, d.z, d.w};
            #pragma unroll
            for (int q = 0; q < 4; q++) {
                int dv = dd[q];
                if (bitmap[(dv >> 5) & (BMW - 1)] & (1 << (dv & 31))) {
                    int idx = -1;
                    for (int j = 0; j < n_s1; j++) if (s1[j] == dv) { idx = j; break; }
                    if (idx >= 0) {
                        int slot = __hip_atomic_fetch_add(&nodecnt[idx], 1,
                                     __ATOMIC_RELAXED, __HIP_MEMORY_SCOPE_AGENT);
                        if (slot < CAPN) {
                            unsigned long long pk =
                                ((unsigned long long)__float_as_uint(ea[eb + q]) << 32) |
                                (unsigned)ei[eb + q];
                            astore_u64(&buck[(size_t)idx * CAPN + slot], pk);
                        }
                    }
                }
            }
        }
        if (gid == 0) {
            for (int e = E4 * 4; e < E; e++) {
                int dv = ei[E + e];
                int idx = -1;
                for (int j = 0; j < n_s1; j++) if (s1[j] == dv) { idx = j; break; }
                if (idx >= 0) {
                    int slot = __hip_atomic_fetch_add(&nodecnt[idx], 1,
                                 __ATOMIC_RELAXED, __HIP_MEMORY_SCOPE_AGENT);
                    if (slot < CAPN) {
                        unsigned long long pk =
                            ((unsigned long long)__float_as_uint(ea[e]) << 32) |
                            (unsigned)ei[e];
                        astore_u64(&buck[(size_t)idx * CAPN + slot], pk);
                    }
                }
            }
        }
    }
    grid_sync(bar, 1);

    int n_s1 = n_sh;
    float eam = eam_sh;

    // ---------------- phase 4: layer 1 + fused layer-2 transforms -----------
    for (int node = bid; node < n_s1; node += NBLK) {
        int v = s1[node];
        int cnt = aload_i(&nodecnt[node]); if (cnt > CAPN) cnt = CAPN;
        for (int k = tid; k < cnt; k += 256) {        // own bucket only
            unsigned long long pk = aload_u64(&buck[(size_t)node * CAPN + k]);
            esrc[k] = (int)(unsigned)(pk & 0xffffffffull);
            eea[k]  = __uint_as_float((unsigned)(pk >> 32));
        }
        __syncthreads();
        int nE = cnt;
        if (tid == 0) { esrc[nE] = v; eea[nE] = eam; }   // self-loop
        __syncthreads();
        nE += 1;

        const float2* x2 = (const float2*)x;
        for (int j = tid; j < nE; j += 256) {            // parallel x gather
            float2 xv = x2[esrc[j]];
            xsA[j] = xv.x; xsB[j] = xv.y;
        }
        __syncthreads();

        float wl0 = Wl1[lane], wl1w = Wl1[64 + lane], bl = bl1[lane];
        float we = We1[lane], at = att1[lane];
        float2 xv = x2[v];
        float xr = xv.x * Wr1[lane] + xv.y * Wr1[64 + lane] + br1[lane];

        for (int k = wq; k < nE; k += 4) {               // scores
            float xl = xsA[k] * wl0 + xsB[k] * wl1w + bl;
            float ev = xl + xr + eea[k] * we;
            ev = ev > 0.f ? ev : 0.2f * ev;
            float p = ev * at;
            for (int o = 32; o >= 1; o >>= 1) p += __shfl_xor(p, o, 64);
            if (lane == 0) scores[k] = p;
        }
        __syncthreads();

        if (wq == 0) {                                   // softmax stats
            float m = -3.4e38f;
            for (int k = lane; k < nE; k += 64) m = fmaxf(m, scores[k]);
            for (int o = 32; o >= 1; o >>= 1) m = fmaxf(m, __shfl_xor(m, o, 64));
            float d = 0.f;
            for (int k = lane; k < nE; k += 64) d += expf(scores[k] - m);
            for (int o = 32; o >= 1; o >>= 1) d += __shfl_xor(d, o, 64);
            if (lane == 0) { m_sh = m; d_sh = d; }
        }
        __syncthreads();
        float m = m_sh, dinv = 1.f / d_sh;

        float acc = 0.f;                                 // weighted sum
        for (int k = wq; k < nE; k += 4) {
            float xl = xsA[k] * wl0 + xsB[k] * wl1w + bl;
            acc += expf(scores[k] - m) * dinv * xl;
        }
        part[wq][lane] = acc;
        __syncthreads();
        if (tid < 64) {
            float h = part[0][lane] + part[1][lane] + part[2][lane] + part[3][lane] + b1[lane];
            hrow[lane] = h > 0.f ? h : 0.f;
        }
        __syncthreads();

        // fused: xl2[node] = Wl2^T hrow + bl2 (k-split across waves), sc1 out
        float p = 0.f;
        int k0 = 16 * wq;
        for (int k = k0; k < k0 + 16; k++) p += hrow[k] * Wl2[k * 64 + lane];
        part[wq][lane] = p;
        __syncthreads();
        if (tid < 64)
            astore_f(&xl2[node * 64 + lane],
                     part[0][lane] + part[1][lane] + part[2][lane] + part[3][lane] + bl2[lane]);

        if (node == 0) {                                 // target transform -> LDS
            __syncthreads();
            float p2 = 0.f;
            for (int k = k0; k < k0 + 16; k++) p2 += hrow[k] * Wr2[k * 64 + lane];
            part[wq][lane] = p2;
            __syncthreads();
            if (tid < 64)
                xr2s[lane] = part[0][lane] + part[1][lane] + part[2][lane] + part[3][lane] + br2[lane];
        }
        __syncthreads();
    }
    grid_sync(bar, 2);

    // -------- phase 5 (block 0, all 4 waves): layer-2 softmax + head --------
    if (bid == 0) {
        int nE2 = c2;
        float* xl2sh = (float*)bitmap;                   // reuse 16 KB
        int rows = n_s1 < 64 ? n_s1 : 64;
        for (int i = tid; i < rows * 64; i += 256) xl2sh[i] = aload_f(&xl2[i]);
        for (int j = tid; j < nE2; j += 256) eea[j] = aload_f(&L2_ea[j]);
        __syncthreads();

        float we = We2[lane], at = att2[lane], xr = xr2s[lane];
        for (int j = wq; j <= nE2; j += 4) {             // scores over waves
            int   idx = (j < nE2) ? l2idx[j] : 0;
            float eav = (j < nE2) ? eea[j]   : eam;
            float xlv = (idx < 64) ? xl2sh[idx * 64 + lane]
                                   : aload_f(&xl2[idx * 64 + lane]);
            float ev = xlv + xr + eav * we;
            ev = ev > 0.f ? ev : 0.2f * ev;
            float p = ev * at;
            for (int o = 32; o >= 1; o >>= 1) p += __shfl_xor(p, o, 64);
            if (lane == 0) scores[j] = p;
        }
        __syncthreads();

        if (wq == 0) {                                   // softmax stats
            int tot = nE2 + 1;
            float m = -3.4e38f;
            for (int j = lane; j < tot; j += 64) m = fmaxf(m, scores[j]);
            for (int o = 32; o >= 1; o >>= 1) m = fmaxf(m, __shfl_xor(m, o, 64));
            float d = 0.f;
            for (int j = lane; j < tot; j += 64) d += expf(scores[j] - m);
            for (int o = 32; o >= 1; o >>= 1) d += __shfl_xor(d, o, 64);
            if (lane == 0) { m_sh = m; d_sh = d; }
        }
        __syncthreads();
        float m = m_sh, dinv = 1.f / d_sh;

        float acc = 0.f;                                 // weighted sum over waves
        for (int j = wq; j <= nE2; j += 4) {
            int idx = (j < nE2) ? l2idx[j] : 0;
            float xlv = (idx < 64) ? xl2sh[idx * 64 + lane]
                                   : aload_f(&xl2[idx * 64 + lane]);
            acc += expf(scores[j] - m) * dinv * xlv;
        }
        part[wq][lane] = acc;
        __syncthreads();
        if (tid < 64) {
            float h = part[0][lane] + part[1][lane] + part[2][lane] + part[3][lane] + b2[lane];
            hrow[lane] = h > 0.f ? h : 0.f;
        }
        __syncthreads();
        if (tid < 128) {                                 // head: [64]@[64,128]+bf
            float r = bf[tid];
            for (int c = 0; c < 64; c++) r += hrow[c] * Wf[c * 128 + tid];
            out[tid] = r;
        }
    }
}

extern "C" void kernel_launch(void* const* d_in, const int* in_sizes, int n_in,
                              void* d_out, int out_size, void* d_ws, size_t ws_size,
                              hipStream_t stream) {
    const float* x    = (const float*)d_in[0];
    const int*   ei   = (const int*)  d_in[1];
    const float* ea   = (const float*)d_in[2];
    const int*   tptr = (const int*)  d_in[3];
    const float* Wl1  = (const float*)d_in[4];
    const float* bl1  = (const float*)d_in[5];
    const float* Wr1  = (const float*)d_in[6];
    const float* br1  = (const float*)d_in[7];
    const float* We1  = (const float*)d_in[8];
    const float* att1 = (const float*)d_in[9];
    const float* b1   = (const float*)d_in[10];
    const float* Wl2  = (const float*)d_in[11];
    const float* bl2  = (const float*)d_in[12];
    const float* Wr2  = (const float*)d_in[13];
    const float* br2  = (const float*)d_in[14];
    const float* We2  = (const float*)d_in[15];
    const float* att2 = (const float*)d_in[16];
    const float* b2   = (const float*)d_in[17];
    const float* Wf   = (const float*)d_in[18];
    const float* bf   = (const float*)d_in[19];

    int E = in_sizes[2];

    char* base = (char*)d_ws;
    int*   hdr      = (int*)base;   base += 256;
    int*   bar      = (int*)base;   base += 8448;   // 64 leaf lines + gen line
    int*   nodecnt  = (int*)base;   base += 2048;   // per-node bucket counters
    float* partials = (float*)base; base += NBLK * sizeof(float);
    int*   L2_src   = (int*)base;   base += 512 * sizeof(int);
    float* L2_ea    = (float*)base; base += 512 * sizeof(float);
    unsigned long long* buck = (unsigned long long*)base;
    base += (size_t)CAPS1 * CAPN * sizeof(unsigned long long);   // 2 MB
    float* xl2      = (float*)base; base += (size_t)CAPS1 * 64 * sizeof(float);

    // Load-bearing: ws re-poisoned to 0xAA before every timed launch;
    // hdr + barrier epochs + bucket counters must start at 0.
    hipMemsetAsync(hdr, 0, 256 + 8448 + 2048, stream);

    hipLaunchKernelGGL(k_mega, dim3(NBLK), dim3(256), 0, stream,
                       x, ei, ea, tptr,
                       Wl1, bl1, Wr1, br1, We1, att1, b1,
                       Wl2, bl2, Wr2, br2, We2, att2, b2,
                       Wf, bf, E,
                       hdr, bar, nodecnt, partials,
                       L2_src, L2_ea,
                       buck, xl2, (float*)d_out);
}